// Round 4
// baseline (535.174 us; speedup 1.0000x reference)
//
#include <hip/hip_runtime.h>
#include <cstdint>
#include <cstddef>

typedef __bf16 bf16x8 __attribute__((ext_vector_type(8)));
typedef float f32x4 __attribute__((ext_vector_type(4)));
typedef unsigned short ushortx8 __attribute__((ext_vector_type(8)));

// float -> bf16, round-half-up
__device__ __forceinline__ unsigned short f2bf(float f) {
  union { float f; unsigned int u; } v; v.f = f;
  return (unsigned short)((v.u + 0x8000u) >> 16);
}

// GELU tanh form (max abs err ~3e-4 vs erf form)
__device__ __forceinline__ float gelu_f(float x) {
  float t = 0.7978845608f * x * (1.0f + 0.044715f * x * x);
  float e = __expf(-2.0f * fabsf(t));
  float th = (1.0f - e) / (1.0f + e);
  th = (t >= 0.0f) ? th : -th;
  return 0.5f * x * (1.0f + th);
}

// async global->LDS, 16B/lane. LDS dest is wave-uniform base + lane*16.
#define GLOAD16(gsrc, ldst)                                                  \
  __builtin_amdgcn_global_load_lds(                                          \
      (const __attribute__((address_space(1))) unsigned int*)(gsrc),         \
      (__attribute__((address_space(3))) unsigned int*)(uintptr_t)(          \
          (char*)(ldst)),                                                    \
      16, 0, 0)

// Swizzled A tile (128 rows x 64 k, bf16): 16B chunk (row R, col8 C) at
// (R>>5)*4096 + ((R&31)*8 + (C ^ (R&7)))*16. Staging lane tid sources col8
// (tid&7)^((tid>>3)&7); 16-row fragment reads hit all 8 bank quads.
#define SWZ_FRAG(base, R, C8)                                                \
  (*(const bf16x8*)((base) + (((R) >> 5) * 4096) +                           \
                    ((((R)&31) * 8 + ((C8) ^ ((R)&7))) * 16)))

// ---------------------------------------------------------------------------
// Conversion: z -> bf16; W1[g,d,h] -> W1t[g,h,d] bf16 (LDS tile transpose);
// Wc[d,g] -> Wct[g,d] bf16
// ---------------------------------------------------------------------------
__global__ __launch_bounds__(256) void k_convert(
    const float* __restrict__ z, const float* __restrict__ W1,
    const float* __restrict__ Wc, unsigned short* __restrict__ zb,
    unsigned short* __restrict__ w1t, unsigned short* __restrict__ wct) {
  int bid = blockIdx.x;
  int tid = threadIdx.x;
  if (bid < 16384) {
    size_t i = ((size_t)bid * 256 + tid) * 8;
    const float4* p = (const float4*)(z + i);
    float4 a = p[0], b = p[1];
    ushortx8 r;
    r[0] = f2bf(a.x); r[1] = f2bf(a.y); r[2] = f2bf(a.z); r[3] = f2bf(a.w);
    r[4] = f2bf(b.x); r[5] = f2bf(b.y); r[6] = f2bf(b.z); r[7] = f2bf(b.w);
    *(ushortx8*)(zb + i) = r;
  } else if (bid < 16384 + 1024) {
    // W1 transpose via 32x32 LDS tile, both sides coalesced
    __shared__ float tile[32][33];
    int b = bid - 16384;
    int gg = b >> 6;
    int t = b & 63;  // 16 d-blk x 4 h-blk
    int d0 = (t >> 2) * 32;
    int h0 = (t & 3) * 32;
    int tx = tid & 31, ty = tid >> 5;
#pragma unroll
    for (int r = 0; r < 4; ++r) {
      int d = d0 + r * 8 + ty;
      tile[r * 8 + ty][tx] = W1[(gg << 16) + d * 128 + h0 + tx];
    }
    __syncthreads();
#pragma unroll
    for (int r = 0; r < 4; ++r) {
      int h = h0 + r * 8 + ty;
      w1t[(gg << 16) + h * 512 + d0 + tx] = f2bf(tile[tx][r * 8 + ty]);
    }
  } else {
#pragma unroll
    for (int j = 0; j < 32; ++j) {
      int i = j * 256 + tid;
      wct[(i & 15) * 512 + (i >> 4)] = f2bf(Wc[i]);
    }
  }
}

// ---------------------------------------------------------------------------
// Fused main kernel. grid = 512 m-tiles x 9 phases, M-MAJOR (phases of one
// m-tile run concurrently -> z-tile served from per-XCD L2, not LLC).
// p<8: expert-pair block (128 rows x 256 cols); p==8: logits+softmax.
// A (z) staged in LDS via global_load_lds; B (w1t, 2MB L2-resident) loaded
// direct global->VGPR with imm offsets -> barrier drains only wait on A.
// ---------------------------------------------------------------------------
__global__ __launch_bounds__(256, 2) void k_main(
    const unsigned short* __restrict__ zb,   // [65536][512] bf16
    const unsigned short* __restrict__ w1t,  // [16][128][512] bf16
    const unsigned short* __restrict__ wct,  // [16][512] bf16
    const float* __restrict__ bc, const float* __restrict__ b1,
    const float* __restrict__ w2, const float* __restrict__ b2,
    float* __restrict__ out) {
  __shared__ alignas(16) char lds[16384];  // A tile only: 128 x 64 bf16
  const int tid = threadIdx.x;
  const int m = blockIdx.x / 9;
  const int p = blockIdx.x % 9;
  const int mbase = m * 128;
  const int wv = tid >> 6;
  const int ln = tid & 63;
  const int l15 = ln & 15;
  const int l4 = ln >> 4;

  // A staging source: row = mbase + it*32 + tid/8, col8 swizzled by row&7
  const int c8s = (((tid & 7) ^ ((tid >> 3) & 7))) * 8;
  const unsigned short* ag = zb + (size_t)(mbase + (tid >> 3)) * 512 + c8s;

  if (p < 8) {
    const int wr = wv >> 1;  // row half
    const int wc = wv & 1;   // expert within pair
    const int e = p * 2 + wc;
    const int rowb = wr * 64;
    // B fragment bases: lane reads w1t[e][n=ct*16+l15][k=l4*8 + imm]
    const unsigned short* bb[8];
#pragma unroll
    for (int ct = 0; ct < 8; ++ct)
      bb[ct] = w1t + e * 65536 + (ct * 16 + l15) * 512 + l4 * 8;
    // A LDS read bases (bytes), per ks; offset(rt) = (rt>>1)*4096+(rt&1)*2048
    const int ab0 =
        (rowb >> 5) * 4096 + (l15 * 8 + (l4 ^ (l15 & 7))) * 16;
    const int ab1 =
        (rowb >> 5) * 4096 + (l15 * 8 + ((4 + l4) ^ (l15 & 7))) * 16;

    f32x4 acc[4][8] = {};
    for (int kt = 0; kt < 8; ++kt) {
      const int ko = kt * 64;
#pragma unroll
      for (int it = 0; it < 4; ++it)
        GLOAD16(ag + it * 32 * 512 + ko, lds + it * 4096 + tid * 16);
      // B ks=0 prefetch (drained together with A at the barrier - free)
      bf16x8 bf0[8];
#pragma unroll
      for (int ct = 0; ct < 8; ++ct)
        bf0[ct] = *(const bf16x8*)(bb[ct] + ko);
      __syncthreads();
      bf16x8 af[4];
#pragma unroll
      for (int rt = 0; rt < 4; ++rt)
        af[rt] = *(const bf16x8*)(lds + ab0 + (rt >> 1) * 4096 +
                                  (rt & 1) * 2048);
      // B ks=1 issue early; latency hidden behind ks=0 MFMA chain
      bf16x8 bf1[8];
#pragma unroll
      for (int ct = 0; ct < 8; ++ct)
        bf1[ct] = *(const bf16x8*)(bb[ct] + ko + 32);
#pragma unroll
      for (int ct = 0; ct < 8; ++ct)
#pragma unroll
        for (int rt = 0; rt < 4; ++rt)
          acc[rt][ct] = __builtin_amdgcn_mfma_f32_16x16x32_bf16(
              af[rt], bf0[ct], acc[rt][ct], 0, 0, 0);
#pragma unroll
      for (int rt = 0; rt < 4; ++rt)
        af[rt] = *(const bf16x8*)(lds + ab1 + (rt >> 1) * 4096 +
                                  (rt & 1) * 2048);
#pragma unroll
      for (int ct = 0; ct < 8; ++ct)
#pragma unroll
        for (int rt = 0; rt < 4; ++rt)
          acc[rt][ct] = __builtin_amdgcn_mfma_f32_16x16x32_bf16(
              af[rt], bf1[ct], acc[rt][ct], 0, 0, 0);
      __syncthreads();
    }
    // epilogue: y[row] = sum_n gelu(h+b1)*W2 + b2, fully in-wave
    float b1v[8], w2v[8];
#pragma unroll
    for (int ct = 0; ct < 8; ++ct) {
      int n = ct * 16 + l15;
      b1v[ct] = b1[e * 128 + n];
      w2v[ct] = w2[e * 128 + n];
    }
    float b2v = b2[e];
#pragma unroll
    for (int rt = 0; rt < 4; ++rt) {
#pragma unroll
      for (int i = 0; i < 4; ++i) {
        float s = 0.0f;
#pragma unroll
        for (int ct = 0; ct < 8; ++ct) {
          float x = acc[rt][ct][i] + b1v[ct];
          s += gelu_f(x) * w2v[ct];
        }
#pragma unroll
        for (int off = 1; off < 16; off <<= 1)
          s += __shfl_xor(s, off, 16);
        if (l15 == 0) {
          int row = rowb + rt * 16 + l4 * 4 + i;
          out[(size_t)2097152 + (size_t)(mbase + row) * 16 + e] = s + b2v;
        }
      }
    }
  } else {
    // ---------------- logits block: logits = z_tile @ Wc + bc, softmax ----
    const unsigned short* wb = wct + l15 * 512 + l4 * 8;  // direct, L2-hot
    f32x4 acc2[2] = {};
    for (int kt = 0; kt < 8; ++kt) {
      const int ko = kt * 64;
#pragma unroll
      for (int it = 0; it < 4; ++it)
        GLOAD16(ag + it * 32 * 512 + ko, lds + it * 4096 + tid * 16);
      bf16x8 bfr0 = *(const bf16x8*)(wb + ko);
      bf16x8 bfr1 = *(const bf16x8*)(wb + ko + 32);
      __syncthreads();
#pragma unroll
      for (int rt = 0; rt < 2; ++rt) {
        bf16x8 a0 = SWZ_FRAG(lds, wv * 32 + rt * 16 + l15, l4);
        acc2[rt] = __builtin_amdgcn_mfma_f32_16x16x32_bf16(a0, bfr0, acc2[rt],
                                                           0, 0, 0);
        bf16x8 a1 = SWZ_FRAG(lds, wv * 32 + rt * 16 + l15, 4 + l4);
        acc2[rt] = __builtin_amdgcn_mfma_f32_16x16x32_bf16(a1, bfr1, acc2[rt],
                                                           0, 0, 0);
      }
      __syncthreads();
    }
    float bcv = bc[l15];
#pragma unroll
    for (int rt = 0; rt < 2; ++rt) {
#pragma unroll
      for (int i = 0; i < 4; ++i) {
        int row = wv * 32 + rt * 16 + l4 * 4 + i;
        float lg = acc2[rt][i] + bcv;
        float mx = lg;
#pragma unroll
        for (int off = 1; off < 16; off <<= 1)
          mx = fmaxf(mx, __shfl_xor(mx, off, 16));
        float ex = __expf(lg - mx);
        float sm = ex;
#pragma unroll
        for (int off = 1; off < 16; off <<= 1)
          sm += __shfl_xor(sm, off, 16);
        size_t ro = (size_t)(mbase + row) * 16 + l15;
        out[ro] = lg;                  // logits
        out[1048576 + ro] = ex / sm;   // p_g
      }
    }
  }
}

// ---------------------------------------------------------------------------
extern "C" void kernel_launch(void* const* d_in, const int* in_sizes, int n_in,
                              void* d_out, int out_size, void* d_ws,
                              size_t ws_size, hipStream_t stream) {
  const float* z = (const float*)d_in[0];
  const float* Wc = (const float*)d_in[1];
  const float* bc = (const float*)d_in[2];
  const float* W1 = (const float*)d_in[3];
  const float* b1 = (const float*)d_in[4];
  const float* W2 = (const float*)d_in[5];
  const float* b2 = (const float*)d_in[6];
  float* out = (float*)d_out;

  unsigned short* zb = (unsigned short*)d_ws;            // 64 MB
  unsigned short* w1t = zb + (size_t)65536 * 512;        // 2 MB
  unsigned short* wct = w1t + (size_t)16 * 128 * 512;    // 16 KB

  k_convert<<<16384 + 1024 + 1, 256, 0, stream>>>(z, W1, Wc, zb, w1t, wct);
  k_main<<<512 * 9, 256, 0, stream>>>(zb, w1t, wct, bc, b1, W2, b2, out);
}

// Round 5
// 401.436 us; speedup vs baseline: 1.3332x; 1.3332x over previous
//
#include <hip/hip_runtime.h>
#include <cstdint>
#include <cstddef>

typedef __bf16 bf16x8 __attribute__((ext_vector_type(8)));
typedef float f32x4 __attribute__((ext_vector_type(4)));
typedef unsigned short ushortx8 __attribute__((ext_vector_type(8)));

// float -> bf16, round-half-up
__device__ __forceinline__ unsigned short f2bf(float f) {
  union { float f; unsigned int u; } v; v.f = f;
  return (unsigned short)((v.u + 0x8000u) >> 16);
}

// GELU, tanh form rewritten via identity 0.5*(1+tanh(t)) == sigmoid(2t):
// gelu = x * rcp(1 + exp2(x * (k + kc*x^2))), k=-2*log2(e)*0.79788456,
// kc=k*0.044715.  Same function as rounds 1-4 (passed), ~half the VALU ops.
__device__ __forceinline__ float gelu_s(float x) {
  float x2 = x * x;
  float p = __builtin_fmaf(x2, -0.10294324f, -2.30220819f);
  float e = __builtin_amdgcn_exp2f(x * p);
  return x * __builtin_amdgcn_rcpf(1.0f + e);
}

// async global->LDS, 16B/lane. LDS dest is wave-uniform base + lane*16.
#define GLOAD16(gsrc, ldst)                                                  \
  __builtin_amdgcn_global_load_lds(                                          \
      (const __attribute__((address_space(1))) unsigned int*)(gsrc),         \
      (__attribute__((address_space(3))) unsigned int*)(uintptr_t)(          \
          (char*)(ldst)),                                                    \
      16, 0, 0)

// Swizzled tile: 16B chunk (row R, col8 C in [0,8)) at
// (R>>5)*4096 + ((R&31)*8 + (C ^ (R&7)))*16. Staging lane tid sources col8
// (tid&7)^((tid>>3)&7); 16-row fragment reads hit all 8 bank quads.
#define SWZ_FRAG(base, R, C8)                                                \
  (*(const bf16x8*)((base) + (((R) >> 5) * 4096) +                           \
                    ((((R)&31) * 8 + ((C8) ^ ((R)&7))) * 16)))

// ---------------------------------------------------------------------------
// Conversion: z -> bf16; W1[g,d,h] -> W1t[g,h,d] bf16 (LDS tile transpose);
// Wc[d,g] -> Wct[g,d] bf16
// ---------------------------------------------------------------------------
__global__ __launch_bounds__(256) void k_convert(
    const float* __restrict__ z, const float* __restrict__ W1,
    const float* __restrict__ Wc, unsigned short* __restrict__ zb,
    unsigned short* __restrict__ w1t, unsigned short* __restrict__ wct) {
  int bid = blockIdx.x;
  int tid = threadIdx.x;
  if (bid < 16384) {
    size_t i = ((size_t)bid * 256 + tid) * 8;
    const float4* p = (const float4*)(z + i);
    float4 a = p[0], b = p[1];
    ushortx8 r;
    r[0] = f2bf(a.x); r[1] = f2bf(a.y); r[2] = f2bf(a.z); r[3] = f2bf(a.w);
    r[4] = f2bf(b.x); r[5] = f2bf(b.y); r[6] = f2bf(b.z); r[7] = f2bf(b.w);
    *(ushortx8*)(zb + i) = r;
  } else if (bid < 16384 + 1024) {
    // W1 transpose via 32x32 LDS tile, both sides coalesced
    __shared__ float tile[32][33];
    int b = bid - 16384;
    int gg = b >> 6;
    int t = b & 63;  // 16 d-blk x 4 h-blk
    int d0 = (t >> 2) * 32;
    int h0 = (t & 3) * 32;
    int tx = tid & 31, ty = tid >> 5;
#pragma unroll
    for (int r = 0; r < 4; ++r) {
      int d = d0 + r * 8 + ty;
      tile[r * 8 + ty][tx] = W1[(gg << 16) + d * 128 + h0 + tx];
    }
    __syncthreads();
#pragma unroll
    for (int r = 0; r < 4; ++r) {
      int h = h0 + r * 8 + ty;
      w1t[(gg << 16) + h * 512 + d0 + tx] = f2bf(tile[tx][r * 8 + ty]);
    }
  } else {
#pragma unroll
    for (int j = 0; j < 32; ++j) {
      int i = j * 256 + tid;
      wct[(i & 15) * 512 + (i >> 4)] = f2bf(Wc[i]);
    }
  }
}

// ---------------------------------------------------------------------------
// Fused main kernel, p-major grid:
//   bid < 512            : logits+softmax block, 128 rows
//   bid >= 512           : expert-pair block, 64 rows x 256 cols (2 experts);
//                          p = (bid-512)>>10, m = (bid-512)&1023
// A staged in LDS (8KB), B staged in LDS (32KB), swizzled; 3 blocks/CU.
// ---------------------------------------------------------------------------
__global__ __launch_bounds__(256, 3) void k_main(
    const unsigned short* __restrict__ zb,   // [65536][512] bf16
    const unsigned short* __restrict__ w1t,  // [16][128][512] bf16
    const unsigned short* __restrict__ wct,  // [16][512] bf16
    const float* __restrict__ bc, const float* __restrict__ b1,
    const float* __restrict__ w2, const float* __restrict__ b2,
    float* __restrict__ out) {
  __shared__ alignas(16) char lds[8192 + 32768 + 1024];  // A | B | ylds
  const int tid = threadIdx.x;
  const int wq = tid >> 6;
  const int ln = tid & 63;
  const int l15 = ln & 15;
  const int l4 = ln >> 4;
  const int c8s = (((tid & 7) ^ ((tid >> 3) & 7))) * 8;
  char* ldsB = lds + 8192;

  if (blockIdx.x >= 512) {
    // ------- expert-pair block: h = z_tile @ W1pair^T, gelu, dot W2 -------
    const int eb = blockIdx.x - 512;
    const int p = eb >> 10;
    const int mbase = (eb & 1023) * 64;
    const unsigned short* ag = zb + (size_t)(mbase + (tid >> 3)) * 512 + c8s;
    const unsigned short* bg = w1t + p * 131072 + (tid >> 3) * 512 + c8s;
    const int e = p * 2 + (wq >> 1);      // expert of this wave
    const int nb = (wq & 1) * 64;         // col-half within expert
    f32x4 acc[4][4] = {};
    for (int kt = 0; kt < 8; ++kt) {
      const int ko = kt * 64;
#pragma unroll
      for (int it = 0; it < 2; ++it)
        GLOAD16(ag + it * 32 * 512 + ko, lds + it * 4096 + tid * 16);
#pragma unroll
      for (int it = 0; it < 8; ++it)
        GLOAD16(bg + it * 32 * 512 + ko, ldsB + it * 4096 + tid * 16);
      __syncthreads();
#pragma unroll
      for (int ks = 0; ks < 2; ++ks) {
        bf16x8 af[4];
#pragma unroll
        for (int rt = 0; rt < 4; ++rt)
          af[rt] = SWZ_FRAG(lds, rt * 16 + l15, ks * 4 + l4);
#pragma unroll
        for (int ct = 0; ct < 4; ++ct) {
          bf16x8 bf = SWZ_FRAG(ldsB, wq * 64 + ct * 16 + l15, ks * 4 + l4);
#pragma unroll
          for (int rt = 0; rt < 4; ++rt)
            acc[rt][ct] = __builtin_amdgcn_mfma_f32_16x16x32_bf16(
                af[rt], bf, acc[rt][ct], 0, 0, 0);
        }
      }
      __syncthreads();
    }
    // epilogue: partial y over this wave's 64 cols, then cross-wave combine
    float b1v[4], w2v[4];
#pragma unroll
    for (int ct = 0; ct < 4; ++ct) {
      int n = nb + ct * 16 + l15;
      b1v[ct] = b1[e * 128 + n];
      w2v[ct] = w2[e * 128 + n];
    }
    float* ylds = (float*)(lds + 40960);  // [4 waves][64 rows]
#pragma unroll
    for (int rt = 0; rt < 4; ++rt) {
#pragma unroll
      for (int i = 0; i < 4; ++i) {
        float s = 0.0f;
#pragma unroll
        for (int ct = 0; ct < 4; ++ct)
          s += gelu_s(acc[rt][ct][i] + b1v[ct]) * w2v[ct];
#pragma unroll
        for (int off = 1; off < 16; off <<= 1)
          s += __shfl_xor(s, off, 16);
        if (l15 == 0) ylds[wq * 64 + rt * 16 + l4 * 4 + i] = s;
      }
    }
    __syncthreads();
    if (tid < 128) {
      int row = tid & 63, ee = tid >> 6;
      float y = ylds[ee * 128 + row] + ylds[ee * 128 + 64 + row] +
                b2[p * 2 + ee];
      out[(size_t)2097152 + (size_t)(mbase + row) * 16 + p * 2 + ee] = y;
    }
  } else {
    // ---------------- logits block: logits = z_tile @ Wc + bc, softmax ----
    const int mbase = blockIdx.x * 128;
    const unsigned short* ag = zb + (size_t)(mbase + (tid >> 3)) * 512 + c8s;
    const unsigned short* wb = wct + l15 * 512 + l4 * 8;  // direct, L2-hot
    f32x4 acc2[2] = {};
    for (int kt = 0; kt < 8; ++kt) {
      const int ko = kt * 64;
#pragma unroll
      for (int it = 0; it < 4; ++it)
        GLOAD16(ag + it * 32 * 512 + ko, lds + it * 4096 + tid * 16);
      bf16x8 bfr0 = *(const bf16x8*)(wb + ko);
      bf16x8 bfr1 = *(const bf16x8*)(wb + ko + 32);
      __syncthreads();
#pragma unroll
      for (int rt = 0; rt < 2; ++rt) {
        bf16x8 a0 = SWZ_FRAG(lds, wq * 32 + rt * 16 + l15, l4);
        acc2[rt] = __builtin_amdgcn_mfma_f32_16x16x32_bf16(a0, bfr0, acc2[rt],
                                                           0, 0, 0);
        bf16x8 a1 = SWZ_FRAG(lds, wq * 32 + rt * 16 + l15, 4 + l4);
        acc2[rt] = __builtin_amdgcn_mfma_f32_16x16x32_bf16(a1, bfr1, acc2[rt],
                                                           0, 0, 0);
      }
      __syncthreads();
    }
    float bcv = bc[l15];
#pragma unroll
    for (int rt = 0; rt < 2; ++rt) {
#pragma unroll
      for (int i = 0; i < 4; ++i) {
        int row = wq * 32 + rt * 16 + l4 * 4 + i;
        float lg = acc2[rt][i] + bcv;
        float mx = lg;
#pragma unroll
        for (int off = 1; off < 16; off <<= 1)
          mx = fmaxf(mx, __shfl_xor(mx, off, 16));
        float ex = __expf(lg - mx);
        float sm = ex;
#pragma unroll
        for (int off = 1; off < 16; off <<= 1)
          sm += __shfl_xor(sm, off, 16);
        size_t ro = (size_t)(mbase + row) * 16 + l15;
        out[ro] = lg;                  // logits
        out[1048576 + ro] = ex / sm;   // p_g
      }
    }
  }
}

// ---------------------------------------------------------------------------
extern "C" void kernel_launch(void* const* d_in, const int* in_sizes, int n_in,
                              void* d_out, int out_size, void* d_ws,
                              size_t ws_size, hipStream_t stream) {
  const float* z = (const float*)d_in[0];
  const float* Wc = (const float*)d_in[1];
  const float* bc = (const float*)d_in[2];
  const float* W1 = (const float*)d_in[3];
  const float* b1 = (const float*)d_in[4];
  const float* W2 = (const float*)d_in[5];
  const float* b2 = (const float*)d_in[6];
  float* out = (float*)d_out;

  unsigned short* zb = (unsigned short*)d_ws;            // 64 MB
  unsigned short* w1t = zb + (size_t)65536 * 512;        // 2 MB
  unsigned short* wct = w1t + (size_t)16 * 128 * 512;    // 16 KB

  k_convert<<<16384 + 1024 + 1, 256, 0, stream>>>(z, W1, Wc, zb, w1t, wct);
  k_main<<<512 + 8 * 1024, 256, 0, stream>>>(zb, w1t, wct, bc, b1, W2, b2,
                                             out);
}